// Round 4
// baseline (824.906 us; speedup 1.0000x reference)
//
#include <hip/hip_runtime.h>
#include <cstdint>
#include <cstddef>

typedef _Float16 f16;
typedef _Float16 f16x4 __attribute__((ext_vector_type(4)));
typedef _Float16 f16x8 __attribute__((ext_vector_type(8)));
typedef float f32x4 __attribute__((ext_vector_type(4)));

// ---------------------------------------------------------------------------
// async global->LDS, 16B per lane. LDS dest is WAVE-UNIFORM base; HW writes
// lane i at base + i*16 (m97/m104 semantics).
// ---------------------------------------------------------------------------
__device__ __forceinline__ void gl2lds16(const void* g, void* l) {
  __builtin_amdgcn_global_load_lds(
      (const __attribute__((address_space(1))) void*)(uintptr_t)g,
      (__attribute__((address_space(3))) void*)(uintptr_t)l,
      16, 0, 0);
}

// ---------------------------------------------------------------------------
// Weight prep via LDS-bounce transpose. Tile 32 o x 32 i per block.
// Reads coef/sb/ss coalesced, writes Wt[o][i*9+t] in 576B runs.
// Wt[o][i*9+0] = sb[i,o]; Wt[o][i*9+1+g] = coef[i,o,g]*ss[i,o]  (R1-verified
// plain Bt layout).
// ---------------------------------------------------------------------------
__global__ __launch_bounds__(256) void kan_prep2(
    const float* __restrict__ coef, const float* __restrict__ sb,
    const float* __restrict__ ss, f16* __restrict__ Wt,
    int out, int K9)
{
  __shared__ float s_sb[32][32];   // [i][o]
  __shared__ float s_ss[32][32];
  __shared__ f16 s_w[32][288];     // [o][i*9+t]
  const int t  = threadIdx.x;
  const int o0 = blockIdx.x * 32, i0 = blockIdx.y * 32;

  {  // sb/ss tiles: one float4 per thread per array
    int il = t >> 3, oc = (t & 7) * 4;
    float4 vb = *(const float4*)(sb + (size_t)(i0 + il) * out + o0 + oc);
    float4 vs = *(const float4*)(ss + (size_t)(i0 + il) * out + o0 + oc);
    s_sb[il][oc + 0] = vb.x; s_sb[il][oc + 1] = vb.y;
    s_sb[il][oc + 2] = vb.z; s_sb[il][oc + 3] = vb.w;
    s_ss[il][oc + 0] = vs.x; s_ss[il][oc + 1] = vs.y;
    s_ss[il][oc + 2] = vs.z; s_ss[il][oc + 3] = vs.w;
  }
  __syncthreads();

  // coef tile: 32i x 32o x 8g = 2048 float4, coalesced; scale & scatter to LDS
#pragma unroll
  for (int j = 0; j < 8; ++j) {
    int f  = j * 256 + t;
    int il = f >> 6, c = f & 63;
    int ol = c >> 1, gh = (c & 1) * 4;
    float4 v = *(const float4*)(coef + ((size_t)(i0 + il) * out + (o0 + ol)) * 8 + gh);
    float ssv = s_ss[il][ol];
    f16* dst = &s_w[ol][il * 9 + 1 + gh];
    dst[0] = (f16)(v.x * ssv); dst[1] = (f16)(v.y * ssv);
    dst[2] = (f16)(v.z * ssv); dst[3] = (f16)(v.w * ssv);
  }
#pragma unroll
  for (int j = 0; j < 4; ++j) {  // sb -> slot 0
    int e = j * 256 + t; int il = e >> 5, ol = e & 31;
    s_w[ol][il * 9] = (f16)s_sb[il][ol];
  }
  __syncthreads();

  {  // write: per o-row 288 f16 contiguous; 8 threads x 36 f16 (9 x 8B stores)
    int o = t >> 3, part = t & 7;
    f16* dst = Wt + (size_t)(o0 + o) * K9 + (size_t)i0 * 9 + part * 36;
    const f16* src = &s_w[o][part * 36];
#pragma unroll
    for (int q = 0; q < 9; ++q)
      *(f16x4*)(dst + q * 4) = *(const f16x4*)(src + q * 4);
  }
}

// ---------------------------------------------------------------------------
// Features: per x -> [silu(x), B3_0(x)..B3_7(x)] fp16, row-major F[b][i*9+t].
// Uniform pykan grid hardcoded: t_j = (j-3)*0.4 - 1.
// ---------------------------------------------------------------------------
__global__ __launch_bounds__(256) void kan_feat(
    const float* __restrict__ X, f16* __restrict__ F,
    int shift, int K9, int iBase)
{
  int idx = blockIdx.x * 256 + threadIdx.x;
  int b  = idx >> shift;
  int ii = idx & ((1 << shift) - 1);
  float x = X[idx];

  float sig  = 1.0f / (1.0f + __expf(-x));
  float silu = x * sig;

  float t[12];
#pragma unroll
  for (int j = 0; j < 12; ++j) t[j] = (float)(j - 3) * 0.4f - 1.0f;
  float b0[11];
#pragma unroll
  for (int j = 0; j < 11; ++j)
    b0[j] = (x >= t[j] && x < t[j + 1]) ? 1.0f : 0.0f;
  float b1[10];
#pragma unroll
  for (int j = 0; j < 10; ++j)
    b1[j] = (x - t[j]) * 2.5f * b0[j] + (t[j + 2] - x) * 2.5f * b0[j + 1];
  float b2[9];
#pragma unroll
  for (int j = 0; j < 9; ++j)
    b2[j] = (x - t[j]) * 1.25f * b1[j] + (t[j + 3] - x) * 1.25f * b1[j + 1];
  float b3[8];
#pragma unroll
  for (int j = 0; j < 8; ++j)
    b3[j] = (x - t[j]) * (1.0f / 1.2f) * b2[j] +
            (t[j + 4] - x) * (1.0f / 1.2f) * b2[j + 1];

  f16* o = F + (size_t)b * K9 + (size_t)(iBase + ii) * 9;
  o[0] = (f16)silu;
#pragma unroll
  for (int g = 0; g < 8; ++g) o[1 + g] = (f16)b3[g];
}

// ---------------------------------------------------------------------------
// GEMM: C[M,N] += A[M,K] * Bt[N,K]^T, fp16 in / fp32 out.
// Block 256x128, BK=32, 256 thr = 4 waves (2Mx2N), wave tile 128x64 (8x4).
// Both A and B staged via global_load_lds (VMEM = 192 B/MFMA, was 384 in R3);
// one barrier per K-step, double-buffered. XOR swizzle chunk^=( (row>>1)&3 )
// at SOURCE address -> frag ds_read_b128 spreads 2 lanes per 16B-slot (free).
// R3 post-mortem: VMEM-bound at ~80 B/cy/CU (B-direct 256 B/MFMA).
// ---------------------------------------------------------------------------
template <int SPLITK>
__global__ __launch_bounds__(256, 2) void kan_gemm(
    const f16* __restrict__ A, const f16* __restrict__ Bt,
    float* __restrict__ C, int N, int K)
{
  __shared__ __align__(16) f16 lds[2][12288];  // [buf][ A:256x32 | B:128x32 ]
  const int tid   = threadIdx.x;
  const int lane  = tid & 63;
  const int w     = tid >> 6;
  const int waveM = w >> 1, waveN = w & 1;
  const int l16   = lane & 15, quad = lane >> 4;
  const size_t mBase = (size_t)blockIdx.y * 256;
  const size_t nBase = (size_t)blockIdx.x * 128;
  const int kChunk = K / SPLITK;
  const int k0     = blockIdx.z * kChunk;
  const int kSteps = kChunk >> 5;

  // staging chunk maps (16B chunks, swizzled at source)
  const f16* gA[4]; int lA[4];
#pragma unroll
  for (int r = 0; r < 4; ++r) {
    int g = r * 256 + tid, row = g >> 2;
    int cs = (g & 3) ^ ((row >> 1) & 3);
    gA[r] = A + (mBase + row) * (size_t)K + k0 + cs * 8;
    lA[r] = (r * 256 + (tid & ~63)) * 8;
  }
  const f16* gB[2]; int lB[2];
#pragma unroll
  for (int r = 0; r < 2; ++r) {
    int g = r * 256 + tid, col = g >> 2;
    int cs = (g & 3) ^ ((col >> 1) & 3);
    gB[r] = Bt + (nBase + col) * (size_t)K + k0 + cs * 8;
    lB[r] = 8192 + (r * 256 + (tid & ~63)) * 8;
  }

  f32x4 acc[8][4] = {};

  {  // preload step 0 into buf 0
    f16* b = lds[0];
#pragma unroll
    for (int r = 0; r < 4; ++r) gl2lds16(gA[r], b + lA[r]);
#pragma unroll
    for (int r = 0; r < 2; ++r) gl2lds16(gB[r], b + lB[r]);
  }

  for (int s = 0; s < kSteps; ++s) {
    __syncthreads();  // buf[s&1] staged
    if (s + 1 < kSteps) {
      int kk = (s + 1) * 32;
      f16* b = lds[(s + 1) & 1];
#pragma unroll
      for (int r = 0; r < 4; ++r) gl2lds16(gA[r] + kk, b + lA[r]);
#pragma unroll
      for (int r = 0; r < 2; ++r) gl2lds16(gB[r] + kk, b + lB[r]);
    }
    const f16* buf = lds[s & 1];
    f16x8 bf[4];
#pragma unroll
    for (int ni = 0; ni < 4; ++ni) {
      int col = waveN * 64 + ni * 16 + l16;
      bf[ni] = *(const f16x8*)(buf + 8192 + col * 32 + (quad ^ ((col >> 1) & 3)) * 8);
    }
#pragma unroll
    for (int mi = 0; mi < 8; ++mi) {
      int row = waveM * 128 + mi * 16 + l16;
      f16x8 af = *(const f16x8*)(buf + row * 32 + (quad ^ ((row >> 1) & 3)) * 8);
#pragma unroll
      for (int ni = 0; ni < 4; ++ni)
        acc[mi][ni] = __builtin_amdgcn_mfma_f32_16x16x32_f16(
            af, bf[ni], acc[mi][ni], 0, 0, 0);
    }
  }

#pragma unroll
  for (int mi = 0; mi < 8; ++mi) {
    size_t row = mBase + waveM * 128 + mi * 16 + quad * 4;
#pragma unroll
    for (int ni = 0; ni < 4; ++ni) {
      size_t col = nBase + waveN * 64 + ni * 16 + l16;
#pragma unroll
      for (int r = 0; r < 4; ++r)
        unsafeAtomicAdd(C + (row + r) * N + col, acc[mi][ni][r]);
    }
  }
}

// ---------------------------------------------------------------------------
// Orchestration. WS: Wt (18.9MB) | F (75.5MB) | actA | actB (16.8MB each).
// Grid (8,16,6): 768 blocks, 2 resident/CU (VGPR~200, LDS 48KB). blockIdx.x
// fastest -> N-strip per XCD (B strip 2.25MB in 4MB L2).
// ---------------------------------------------------------------------------
extern "C" void kernel_launch(void* const* d_in, const int* in_sizes, int n_in,
                              void* d_out, int out_size, void* d_ws, size_t ws_size,
                              hipStream_t stream)
{
  const float* y = (const float*)d_in[0];
  const float* u = (const float*)d_in[1];
  const float* coef[4]; const float* sb[4]; const float* ss[4];
  for (int l = 0; l < 4; ++l) {
    coef[l] = (const float*)d_in[2 + 4 * l];
    sb[l]   = (const float*)d_in[3 + 4 * l];
    ss[l]   = (const float*)d_in[4 + 4 * l];
  }
  char* ws = (char*)d_ws;
  f16*   Wt   = (f16*)(ws);
  f16*   F    = (f16*)(ws + 18874368);                        // 9216*1024*2
  float* actA = (float*)(ws + 18874368 + 75497472);           // + 4096*9216*2
  float* actB = (float*)(ws + 18874368 + 75497472 + 16777216);
  float* out  = (float*)d_out;
  const size_t actBytes = (size_t)4096 * 1024 * 4;

  // Layer 0: in=512 (concat y|u), out=1024, K=4608. splitK=6 (kChunk 768).
  kan_prep2<<<dim3(32, 16), 256, 0, stream>>>(coef[0], sb[0], ss[0], Wt, 1024, 4608);
  kan_feat<<<4096 * 256 / 256, 256, 0, stream>>>(y, F, 8, 4608, 0);
  kan_feat<<<4096 * 256 / 256, 256, 0, stream>>>(u, F, 8, 4608, 256);
  hipMemsetAsync(actA, 0, actBytes, stream);
  kan_gemm<6><<<dim3(8, 16, 6), 256, 0, stream>>>(F, Wt, actA, 1024, 4608);

  // Layer 1: in=1024, out=1024, K=9216. splitK=6 (kChunk 1536).
  kan_prep2<<<dim3(32, 32), 256, 0, stream>>>(coef[1], sb[1], ss[1], Wt, 1024, 9216);
  kan_feat<<<4096 * 1024 / 256, 256, 0, stream>>>(actA, F, 10, 9216, 0);
  hipMemsetAsync(actB, 0, actBytes, stream);
  kan_gemm<6><<<dim3(8, 16, 6), 256, 0, stream>>>(F, Wt, actB, 1024, 9216);

  // Layer 2: in=1024, out=1024, K=9216. splitK=6.
  kan_prep2<<<dim3(32, 32), 256, 0, stream>>>(coef[2], sb[2], ss[2], Wt, 1024, 9216);
  kan_feat<<<4096 * 1024 / 256, 256, 0, stream>>>(actB, F, 10, 9216, 0);
  hipMemsetAsync(actA, 0, actBytes, stream);
  kan_gemm<6><<<dim3(8, 16, 6), 256, 0, stream>>>(F, Wt, actA, 1024, 9216);

  // Layer 3: in=1024, out=256, K=9216. splitK=24 -> 768 blocks (kChunk 384).
  kan_prep2<<<dim3(8, 32), 256, 0, stream>>>(coef[3], sb[3], ss[3], Wt, 256, 9216);
  kan_feat<<<4096 * 1024 / 256, 256, 0, stream>>>(actA, F, 10, 9216, 0);
  hipMemsetAsync(d_out, 0, (size_t)out_size * sizeof(float), stream);
  kan_gemm<24><<<dim3(2, 16, 24), 256, 0, stream>>>(F, Wt, out, 256, 9216);
}

// Round 5
// 709.286 us; speedup vs baseline: 1.1630x; 1.1630x over previous
//
#include <hip/hip_runtime.h>
#include <cstdint>
#include <cstddef>

typedef _Float16 f16;
typedef _Float16 f16x4 __attribute__((ext_vector_type(4)));
typedef _Float16 f16x8 __attribute__((ext_vector_type(8)));
typedef float f32x4 __attribute__((ext_vector_type(4)));

// ---------------------------------------------------------------------------
// async global->LDS, 16B per lane. LDS dest is WAVE-UNIFORM base; HW writes
// lane i at base + i*16 (m97/m104 semantics).
// ---------------------------------------------------------------------------
__device__ __forceinline__ void gl2lds16(const void* g, void* l) {
  __builtin_amdgcn_global_load_lds(
      (const __attribute__((address_space(1))) void*)(uintptr_t)g,
      (__attribute__((address_space(3))) void*)(uintptr_t)l,
      16, 0, 0);
}

// ---------------------------------------------------------------------------
// Weight prep via LDS-bounce transpose. Tile 32 o x 32 i per block.
// Wt[o][i*9+0] = sb[i,o]; Wt[o][i*9+1+g] = coef[i,o,g]*ss[i,o].
// ---------------------------------------------------------------------------
__global__ __launch_bounds__(256) void kan_prep2(
    const float* __restrict__ coef, const float* __restrict__ sb,
    const float* __restrict__ ss, f16* __restrict__ Wt,
    int out, int K9)
{
  __shared__ float s_sb[32][32];   // [i][o]
  __shared__ float s_ss[32][32];
  __shared__ f16 s_w[32][288];     // [o][i*9+t]
  const int t  = threadIdx.x;
  const int o0 = blockIdx.x * 32, i0 = blockIdx.y * 32;

  {
    int il = t >> 3, oc = (t & 7) * 4;
    float4 vb = *(const float4*)(sb + (size_t)(i0 + il) * out + o0 + oc);
    float4 vs = *(const float4*)(ss + (size_t)(i0 + il) * out + o0 + oc);
    s_sb[il][oc + 0] = vb.x; s_sb[il][oc + 1] = vb.y;
    s_sb[il][oc + 2] = vb.z; s_sb[il][oc + 3] = vb.w;
    s_ss[il][oc + 0] = vs.x; s_ss[il][oc + 1] = vs.y;
    s_ss[il][oc + 2] = vs.z; s_ss[il][oc + 3] = vs.w;
  }
  __syncthreads();

#pragma unroll
  for (int j = 0; j < 8; ++j) {
    int f  = j * 256 + t;
    int il = f >> 6, c = f & 63;
    int ol = c >> 1, gh = (c & 1) * 4;
    float4 v = *(const float4*)(coef + ((size_t)(i0 + il) * out + (o0 + ol)) * 8 + gh);
    float ssv = s_ss[il][ol];
    f16* dst = &s_w[ol][il * 9 + 1 + gh];
    dst[0] = (f16)(v.x * ssv); dst[1] = (f16)(v.y * ssv);
    dst[2] = (f16)(v.z * ssv); dst[3] = (f16)(v.w * ssv);
  }
#pragma unroll
  for (int j = 0; j < 4; ++j) {
    int e = j * 256 + t; int il = e >> 5, ol = e & 31;
    s_w[ol][il * 9] = (f16)s_sb[il][ol];
  }
  __syncthreads();

  {
    int o = t >> 3, part = t & 7;
    f16* dst = Wt + (size_t)(o0 + o) * K9 + (size_t)i0 * 9 + part * 36;
    const f16* src = &s_w[o][part * 36];
#pragma unroll
    for (int q = 0; q < 9; ++q)
      *(f16x4*)(dst + q * 4) = *(const f16x4*)(src + q * 4);
  }
}

// ---------------------------------------------------------------------------
// Features: per x -> [silu(x), B3_0(x)..B3_7(x)] fp16, row-major F[b][i*9+t].
// Uniform pykan grid hardcoded: t_j = (j-3)*0.4 - 1.
// ---------------------------------------------------------------------------
__global__ __launch_bounds__(256) void kan_feat(
    const float* __restrict__ X, f16* __restrict__ F,
    int shift, int K9, int iBase)
{
  int idx = blockIdx.x * 256 + threadIdx.x;
  int b  = idx >> shift;
  int ii = idx & ((1 << shift) - 1);
  float x = X[idx];

  float sig  = 1.0f / (1.0f + __expf(-x));
  float silu = x * sig;

  float t[12];
#pragma unroll
  for (int j = 0; j < 12; ++j) t[j] = (float)(j - 3) * 0.4f - 1.0f;
  float b0[11];
#pragma unroll
  for (int j = 0; j < 11; ++j)
    b0[j] = (x >= t[j] && x < t[j + 1]) ? 1.0f : 0.0f;
  float b1[10];
#pragma unroll
  for (int j = 0; j < 10; ++j)
    b1[j] = (x - t[j]) * 2.5f * b0[j] + (t[j + 2] - x) * 2.5f * b0[j + 1];
  float b2[9];
#pragma unroll
  for (int j = 0; j < 9; ++j)
    b2[j] = (x - t[j]) * 1.25f * b1[j] + (t[j + 3] - x) * 1.25f * b1[j + 1];
  float b3[8];
#pragma unroll
  for (int j = 0; j < 8; ++j)
    b3[j] = (x - t[j]) * (1.0f / 1.2f) * b2[j] +
            (t[j + 4] - x) * (1.0f / 1.2f) * b2[j + 1];

  f16* o = F + (size_t)b * K9 + (size_t)(iBase + ii) * 9;
  o[0] = (f16)silu;
#pragma unroll
  for (int g = 0; g < 8; ++g) o[1 + g] = (f16)b3[g];
}

// ---------------------------------------------------------------------------
// GEMM: C[M,N] += A[M,K] * Bt[N,K]^T, fp16 in / fp32 out.
// Block 256x128, BK=32, 4 waves (2Mx2N), wave tile 128x64, acc[8][4].
// MANUAL PIPELINE (AITER-style, replaces __syncthreads' vmcnt(0) drain):
//   iter s: s_waitcnt vmcnt(6) [step-s loads landed, step-s+1 in flight]
//           s_barrier; ds_read frags buf[s&1]; s_waitcnt lgkmcnt(0);
//           s_barrier; issue step-s+2 loads into buf[s&1]; 32 MFMA.
// 2 steps always in flight -> load latency hidden within one block.
// R4 post-mortem: corrected MFMA cost = 19.4 SIMD-cy -> per step MFMA 620
// SIMD-cy dominates VMEM (24 KB, 40U B/cy) and LDS (72 KB, 116U B/cy);
// all prior rounds were latency-bound, not BW-bound.
// XOR swizzle chunk^=((row>>1)&3) at source: R4-verified 0 bank conflicts.
// ---------------------------------------------------------------------------
template <int SPLITK>
__global__ __launch_bounds__(256, 2) void kan_gemm(
    const f16* __restrict__ A, const f16* __restrict__ Bt,
    float* __restrict__ C, int N, int K)
{
  __shared__ __align__(16) f16 lds[2][12288];  // [buf][ A:256x32 | B:128x32 ]
  const int tid   = threadIdx.x;
  const int lane  = tid & 63;
  const int w     = tid >> 6;
  const int waveM = w >> 1, waveN = w & 1;
  const int l16   = lane & 15, quad = lane >> 4;
  const size_t mBase = (size_t)blockIdx.y * 256;
  const size_t nBase = (size_t)blockIdx.x * 128;
  const int kChunk = K / SPLITK;
  const int k0     = blockIdx.z * kChunk;
  const int kSteps = kChunk >> 5;

  // staging chunk maps (16B chunks, swizzled at source)
  const f16* gA[4]; int lA[4];
#pragma unroll
  for (int r = 0; r < 4; ++r) {
    int g = r * 256 + tid, row = g >> 2;
    int cs = (g & 3) ^ ((row >> 1) & 3);
    gA[r] = A + (mBase + row) * (size_t)K + k0 + cs * 8;
    lA[r] = (r * 256 + (tid & ~63)) * 8;
  }
  const f16* gB[2]; int lB[2];
#pragma unroll
  for (int r = 0; r < 2; ++r) {
    int g = r * 256 + tid, col = g >> 2;
    int cs = (g & 3) ^ ((col >> 1) & 3);
    gB[r] = Bt + (nBase + col) * (size_t)K + k0 + cs * 8;
    lB[r] = 8192 + (r * 256 + (tid & ~63)) * 8;
  }

  f32x4 acc[8][4] = {};

  {  // preload steps 0 and 1 (kSteps >= 2 always in our shapes)
    f16* b0 = lds[0];
#pragma unroll
    for (int r = 0; r < 4; ++r) gl2lds16(gA[r], b0 + lA[r]);
#pragma unroll
    for (int r = 0; r < 2; ++r) gl2lds16(gB[r], b0 + lB[r]);
    f16* b1 = lds[1];
#pragma unroll
    for (int r = 0; r < 4; ++r) gl2lds16(gA[r] + 32, b1 + lA[r]);
#pragma unroll
    for (int r = 0; r < 2; ++r) gl2lds16(gB[r] + 32, b1 + lB[r]);
  }

  for (int s = 0; s < kSteps; ++s) {
    // wait for step-s's 6 loads; leave step-s+1's 6 in flight (tail: drain)
    if (s + 1 < kSteps) asm volatile("s_waitcnt vmcnt(6)" ::: "memory");
    else                asm volatile("s_waitcnt vmcnt(0)" ::: "memory");
    __builtin_amdgcn_s_barrier();

    const f16* buf = lds[s & 1];
    f16x8 af[8], bf[4];
#pragma unroll
    for (int mi = 0; mi < 8; ++mi) {
      int row = waveM * 128 + mi * 16 + l16;
      af[mi] = *(const f16x8*)(buf + row * 32 + (quad ^ ((row >> 1) & 3)) * 8);
    }
#pragma unroll
    for (int ni = 0; ni < 4; ++ni) {
      int col = waveN * 64 + ni * 16 + l16;
      bf[ni] = *(const f16x8*)(buf + 8192 + col * 32 + (quad ^ ((col >> 1) & 3)) * 8);
    }
    // all frags in regs before anyone overwrites this buffer
    asm volatile("s_waitcnt lgkmcnt(0)" ::: "memory");
    __builtin_amdgcn_s_barrier();

    if (s + 2 < kSteps) {
      int kk = (s + 2) * 32;
      f16* b = lds[s & 1];
#pragma unroll
      for (int r = 0; r < 4; ++r) gl2lds16(gA[r] + kk, b + lA[r]);
#pragma unroll
      for (int r = 0; r < 2; ++r) gl2lds16(gB[r] + kk, b + lB[r]);
    }

#pragma unroll
    for (int mi = 0; mi < 8; ++mi)
#pragma unroll
      for (int ni = 0; ni < 4; ++ni)
        acc[mi][ni] = __builtin_amdgcn_mfma_f32_16x16x32_f16(
            af[mi], bf[ni], acc[mi][ni], 0, 0, 0);
  }

#pragma unroll
  for (int mi = 0; mi < 8; ++mi) {
    size_t row = mBase + waveM * 128 + mi * 16 + quad * 4;
#pragma unroll
    for (int ni = 0; ni < 4; ++ni) {
      size_t col = nBase + waveN * 64 + ni * 16 + l16;
#pragma unroll
      for (int r = 0; r < 4; ++r)
        unsafeAtomicAdd(C + (row + r) * N + col, acc[mi][ni][r]);
    }
  }
}

// ---------------------------------------------------------------------------
// Orchestration. WS: Wt (18.9MB) | F (75.5MB) | actA | actB (16.8MB each).
// Grids: 512 blocks = 2 resident/CU (launch_bounds(256,2); LDS 48KB -> 3 cap,
// VGPR ~216 -> 2). blockIdx.x fastest -> N-strip L2 locality per XCD.
// ---------------------------------------------------------------------------
extern "C" void kernel_launch(void* const* d_in, const int* in_sizes, int n_in,
                              void* d_out, int out_size, void* d_ws, size_t ws_size,
                              hipStream_t stream)
{
  const float* y = (const float*)d_in[0];
  const float* u = (const float*)d_in[1];
  const float* coef[4]; const float* sb[4]; const float* ss[4];
  for (int l = 0; l < 4; ++l) {
    coef[l] = (const float*)d_in[2 + 4 * l];
    sb[l]   = (const float*)d_in[3 + 4 * l];
    ss[l]   = (const float*)d_in[4 + 4 * l];
  }
  char* ws = (char*)d_ws;
  f16*   Wt   = (f16*)(ws);
  f16*   F    = (f16*)(ws + 18874368);                        // 9216*1024*2
  float* actA = (float*)(ws + 18874368 + 75497472);           // + 4096*9216*2
  float* actB = (float*)(ws + 18874368 + 75497472 + 16777216);
  float* out  = (float*)d_out;
  const size_t actBytes = (size_t)4096 * 1024 * 4;

  // Layer 0: in=512 (concat y|u), out=1024, K=4608. splitK=4 (kSteps 36).
  kan_prep2<<<dim3(32, 16), 256, 0, stream>>>(coef[0], sb[0], ss[0], Wt, 1024, 4608);
  kan_feat<<<4096 * 256 / 256, 256, 0, stream>>>(y, F, 8, 4608, 0);
  kan_feat<<<4096 * 256 / 256, 256, 0, stream>>>(u, F, 8, 4608, 256);
  hipMemsetAsync(actA, 0, actBytes, stream);
  kan_gemm<4><<<dim3(8, 16, 4), 256, 0, stream>>>(F, Wt, actA, 1024, 4608);

  // Layer 1: in=1024, out=1024, K=9216. splitK=4 (kSteps 72).
  kan_prep2<<<dim3(32, 32), 256, 0, stream>>>(coef[1], sb[1], ss[1], Wt, 1024, 9216);
  kan_feat<<<4096 * 1024 / 256, 256, 0, stream>>>(actA, F, 10, 9216, 0);
  hipMemsetAsync(actB, 0, actBytes, stream);
  kan_gemm<4><<<dim3(8, 16, 4), 256, 0, stream>>>(F, Wt, actB, 1024, 9216);

  // Layer 2: in=1024, out=1024, K=9216. splitK=4.
  kan_prep2<<<dim3(32, 32), 256, 0, stream>>>(coef[2], sb[2], ss[2], Wt, 1024, 9216);
  kan_feat<<<4096 * 1024 / 256, 256, 0, stream>>>(actB, F, 10, 9216, 0);
  hipMemsetAsync(actA, 0, actBytes, stream);
  kan_gemm<4><<<dim3(8, 16, 4), 256, 0, stream>>>(F, Wt, actA, 1024, 9216);

  // Layer 3: in=1024, out=256, K=9216. splitK=16 -> 512 blocks (kSteps 18).
  kan_prep2<<<dim3(8, 32), 256, 0, stream>>>(coef[3], sb[3], ss[3], Wt, 256, 9216);
  kan_feat<<<4096 * 1024 / 256, 256, 0, stream>>>(actA, F, 10, 9216, 0);
  hipMemsetAsync(d_out, 0, (size_t)out_size * sizeof(float), stream);
  kan_gemm<16><<<dim3(2, 16, 16), 256, 0, stream>>>(F, Wt, out, 256, 9216);
}

// Round 6
// 697.742 us; speedup vs baseline: 1.1822x; 1.0165x over previous
//
#include <hip/hip_runtime.h>
#include <cstdint>
#include <cstddef>

typedef _Float16 f16;
typedef _Float16 f16x4 __attribute__((ext_vector_type(4)));
typedef _Float16 f16x8 __attribute__((ext_vector_type(8)));
typedef float f32x4 __attribute__((ext_vector_type(4)));

// ---------------------------------------------------------------------------
// async global->LDS, 16B per lane. LDS dest is WAVE-UNIFORM base; HW writes
// lane i at base + i*16 (m97/m104 semantics).
// ---------------------------------------------------------------------------
__device__ __forceinline__ void gl2lds16(const void* g, void* l) {
  __builtin_amdgcn_global_load_lds(
      (const __attribute__((address_space(1))) void*)(uintptr_t)g,
      (__attribute__((address_space(3))) void*)(uintptr_t)l,
      16, 0, 0);
}

// ---------------------------------------------------------------------------
// Weight prep via LDS-bounce transpose. Tile 32 o x 32 i per block.
// Wt[o][i*9+0] = sb[i,o]; Wt[o][i*9+1+g] = coef[i,o,g]*ss[i,o].
// ---------------------------------------------------------------------------
__global__ __launch_bounds__(256) void kan_prep2(
    const float* __restrict__ coef, const float* __restrict__ sb,
    const float* __restrict__ ss, f16* __restrict__ Wt,
    int out, int K9)
{
  __shared__ float s_sb[32][32];   // [i][o]
  __shared__ float s_ss[32][32];
  __shared__ f16 s_w[32][288];     // [o][i*9+t]
  const int t  = threadIdx.x;
  const int o0 = blockIdx.x * 32, i0 = blockIdx.y * 32;

  {
    int il = t >> 3, oc = (t & 7) * 4;
    float4 vb = *(const float4*)(sb + (size_t)(i0 + il) * out + o0 + oc);
    float4 vs = *(const float4*)(ss + (size_t)(i0 + il) * out + o0 + oc);
    s_sb[il][oc + 0] = vb.x; s_sb[il][oc + 1] = vb.y;
    s_sb[il][oc + 2] = vb.z; s_sb[il][oc + 3] = vb.w;
    s_ss[il][oc + 0] = vs.x; s_ss[il][oc + 1] = vs.y;
    s_ss[il][oc + 2] = vs.z; s_ss[il][oc + 3] = vs.w;
  }
  __syncthreads();

#pragma unroll
  for (int j = 0; j < 8; ++j) {
    int f  = j * 256 + t;
    int il = f >> 6, c = f & 63;
    int ol = c >> 1, gh = (c & 1) * 4;
    float4 v = *(const float4*)(coef + ((size_t)(i0 + il) * out + (o0 + ol)) * 8 + gh);
    float ssv = s_ss[il][ol];
    f16* dst = &s_w[ol][il * 9 + 1 + gh];
    dst[0] = (f16)(v.x * ssv); dst[1] = (f16)(v.y * ssv);
    dst[2] = (f16)(v.z * ssv); dst[3] = (f16)(v.w * ssv);
  }
#pragma unroll
  for (int j = 0; j < 4; ++j) {
    int e = j * 256 + t; int il = e >> 5, ol = e & 31;
    s_w[ol][il * 9] = (f16)s_sb[il][ol];
  }
  __syncthreads();

  {
    int o = t >> 3, part = t & 7;
    f16* dst = Wt + (size_t)(o0 + o) * K9 + (size_t)i0 * 9 + part * 36;
    const f16* src = &s_w[o][part * 36];
#pragma unroll
    for (int q = 0; q < 9; ++q)
      *(f16x4*)(dst + q * 4) = *(const f16x4*)(src + q * 4);
  }
}

// ---------------------------------------------------------------------------
// Features: per x -> [silu(x), B3_0(x)..B3_7(x)] fp16, row-major F[b][i*9+t].
// Uniform pykan grid hardcoded: t_j = (j-3)*0.4 - 1.
// ---------------------------------------------------------------------------
__global__ __launch_bounds__(256) void kan_feat(
    const float* __restrict__ X, f16* __restrict__ F,
    int shift, int K9, int iBase)
{
  int idx = blockIdx.x * 256 + threadIdx.x;
  int b  = idx >> shift;
  int ii = idx & ((1 << shift) - 1);
  float x = X[idx];

  float sig  = 1.0f / (1.0f + __expf(-x));
  float silu = x * sig;

  float t[12];
#pragma unroll
  for (int j = 0; j < 12; ++j) t[j] = (float)(j - 3) * 0.4f - 1.0f;
  float b0[11];
#pragma unroll
  for (int j = 0; j < 11; ++j)
    b0[j] = (x >= t[j] && x < t[j + 1]) ? 1.0f : 0.0f;
  float b1[10];
#pragma unroll
  for (int j = 0; j < 10; ++j)
    b1[j] = (x - t[j]) * 2.5f * b0[j] + (t[j + 2] - x) * 2.5f * b0[j + 1];
  float b2[9];
#pragma unroll
  for (int j = 0; j < 9; ++j)
    b2[j] = (x - t[j]) * 1.25f * b1[j] + (t[j + 3] - x) * 1.25f * b1[j + 1];
  float b3[8];
#pragma unroll
  for (int j = 0; j < 8; ++j)
    b3[j] = (x - t[j]) * (1.0f / 1.2f) * b2[j] +
            (t[j + 4] - x) * (1.0f / 1.2f) * b2[j + 1];

  f16* o = F + (size_t)b * K9 + (size_t)(iBase + ii) * 9;
  o[0] = (f16)silu;
#pragma unroll
  for (int g = 0; g < 8; ++g) o[1 + g] = (f16)b3[g];
}

// ---------------------------------------------------------------------------
// GEMM: C[M,N] += A[M,K] * Bt[N,K]^T, fp16 in / fp32 out.
// Block 128x128, BK=32, 4 waves (2x2), wave tile 64x64, acc[4][4] (64 VGPR).
// Double-buffered 32 KB LDS, ONE __syncthreads per K-step, prefetch after it
// (R5 proved manual vmcnt == compiler drain; this is the R1/R5 loop shape).
// R5 post-mortem: only untested corner is HIGH OCCUPANCY + 0 conflicts +
// small LDS. __launch_bounds__(256,4) pins VGPR<=128 -> 4 blocks/CU (LDS cap
// 5, VGPR cap 4). splitK -> 1024 blocks; dispatch interleaves different
// (x,y) tiles per CU -> dephased, unlike R2's phase-locked clones.
// XOR swizzle chunk^=((row>>1)&3) at source: R4/R5-verified 0 conflicts.
// ---------------------------------------------------------------------------
template <int SPLITK>
__global__ __launch_bounds__(256, 4) void kan_gemm(
    const f16* __restrict__ A, const f16* __restrict__ Bt,
    float* __restrict__ C, int N, int K)
{
  __shared__ __align__(16) f16 lds[2][8192];  // [buf][ A:128x32 | B:128x32 ]
  const int tid   = threadIdx.x;
  const int lane  = tid & 63;
  const int w     = tid >> 6;
  const int waveM = w >> 1, waveN = w & 1;
  const int l16   = lane & 15, quad = lane >> 4;
  const size_t mBase = (size_t)blockIdx.y * 128;
  const size_t nBase = (size_t)blockIdx.x * 128;
  const int kChunk = K / SPLITK;
  const int k0     = blockIdx.z * kChunk;
  const int kSteps = kChunk >> 5;

  // staging: A = 512 chunks of 16B (2/thread), B same. Swizzled at source.
  const f16* gA[2]; int lA[2];
  const f16* gB[2]; int lB[2];
#pragma unroll
  for (int r = 0; r < 2; ++r) {
    int g = r * 256 + tid, row = g >> 2;
    int cs = (g & 3) ^ ((row >> 1) & 3);
    gA[r] = A + (mBase + row) * (size_t)K + k0 + cs * 8;
    gB[r] = Bt + (nBase + row) * (size_t)K + k0 + cs * 8;
    lA[r] = (r * 256 + (tid & ~63)) * 8;
    lB[r] = 4096 + lA[r];
  }

  f32x4 acc[4][4] = {};

  {  // preload step 0 into buf 0
    f16* b = lds[0];
#pragma unroll
    for (int r = 0; r < 2; ++r) { gl2lds16(gA[r], b + lA[r]); gl2lds16(gB[r], b + lB[r]); }
  }

  for (int s = 0; s < kSteps; ++s) {
    __syncthreads();  // buf[s&1] staged (compiler emits vmcnt/lgkm drain)
    if (s + 1 < kSteps) {
      int kk = (s + 1) * 32;
      f16* b = lds[(s + 1) & 1];
#pragma unroll
      for (int r = 0; r < 2; ++r) {
        gl2lds16(gA[r] + kk, b + lA[r]);
        gl2lds16(gB[r] + kk, b + lB[r]);
      }
    }
    const f16* buf = lds[s & 1];
    f16x8 af[4], bf[4];
#pragma unroll
    for (int mi = 0; mi < 4; ++mi) {
      int row = waveM * 64 + mi * 16 + l16;
      af[mi] = *(const f16x8*)(buf + row * 32 + (quad ^ ((row >> 1) & 3)) * 8);
    }
#pragma unroll
    for (int ni = 0; ni < 4; ++ni) {
      int col = waveN * 64 + ni * 16 + l16;
      bf[ni] = *(const f16x8*)(buf + 4096 + col * 32 + (quad ^ ((col >> 1) & 3)) * 8);
    }
#pragma unroll
    for (int mi = 0; mi < 4; ++mi)
#pragma unroll
      for (int ni = 0; ni < 4; ++ni)
        acc[mi][ni] = __builtin_amdgcn_mfma_f32_16x16x32_f16(
            af[mi], bf[ni], acc[mi][ni], 0, 0, 0);
  }

#pragma unroll
  for (int mi = 0; mi < 4; ++mi) {
    size_t row = mBase + waveM * 64 + mi * 16 + quad * 4;
#pragma unroll
    for (int ni = 0; ni < 4; ++ni) {
      size_t col = nBase + waveN * 64 + ni * 16 + l16;
#pragma unroll
      for (int r = 0; r < 4; ++r)
        unsafeAtomicAdd(C + (row + r) * N + col, acc[mi][ni][r]);
    }
  }
}

// ---------------------------------------------------------------------------
// Orchestration. WS: Wt (18.9MB) | F (75.5MB) | actA | actB (16.8MB each).
// All GEMM grids = 1024 blocks -> 4 resident/CU (16 waves/CU, 50% occ).
// ---------------------------------------------------------------------------
extern "C" void kernel_launch(void* const* d_in, const int* in_sizes, int n_in,
                              void* d_out, int out_size, void* d_ws, size_t ws_size,
                              hipStream_t stream)
{
  const float* y = (const float*)d_in[0];
  const float* u = (const float*)d_in[1];
  const float* coef[4]; const float* sb[4]; const float* ss[4];
  for (int l = 0; l < 4; ++l) {
    coef[l] = (const float*)d_in[2 + 4 * l];
    sb[l]   = (const float*)d_in[3 + 4 * l];
    ss[l]   = (const float*)d_in[4 + 4 * l];
  }
  char* ws = (char*)d_ws;
  f16*   Wt   = (f16*)(ws);
  f16*   F    = (f16*)(ws + 18874368);                        // 9216*1024*2
  float* actA = (float*)(ws + 18874368 + 75497472);           // + 4096*9216*2
  float* actB = (float*)(ws + 18874368 + 75497472 + 16777216);
  float* out  = (float*)d_out;
  const size_t actBytes = (size_t)4096 * 1024 * 4;

  // Layer 0: in=512 (concat y|u), out=1024, K=4608. splitK=4 (kSteps 36).
  kan_prep2<<<dim3(32, 16), 256, 0, stream>>>(coef[0], sb[0], ss[0], Wt, 1024, 4608);
  kan_feat<<<4096 * 256 / 256, 256, 0, stream>>>(y, F, 8, 4608, 0);
  kan_feat<<<4096 * 256 / 256, 256, 0, stream>>>(u, F, 8, 4608, 256);
  hipMemsetAsync(actA, 0, actBytes, stream);
  kan_gemm<4><<<dim3(8, 32, 4), 256, 0, stream>>>(F, Wt, actA, 1024, 4608);

  // Layer 1: in=1024, out=1024, K=9216. splitK=4 (kSteps 72).
  kan_prep2<<<dim3(32, 32), 256, 0, stream>>>(coef[1], sb[1], ss[1], Wt, 1024, 9216);
  kan_feat<<<4096 * 1024 / 256, 256, 0, stream>>>(actA, F, 10, 9216, 0);
  hipMemsetAsync(actB, 0, actBytes, stream);
  kan_gemm<4><<<dim3(8, 32, 4), 256, 0, stream>>>(F, Wt, actB, 1024, 9216);

  // Layer 2: in=1024, out=1024, K=9216. splitK=4.
  kan_prep2<<<dim3(32, 32), 256, 0, stream>>>(coef[2], sb[2], ss[2], Wt, 1024, 9216);
  kan_feat<<<4096 * 1024 / 256, 256, 0, stream>>>(actB, F, 10, 9216, 0);
  hipMemsetAsync(actA, 0, actBytes, stream);
  kan_gemm<4><<<dim3(8, 32, 4), 256, 0, stream>>>(F, Wt, actA, 1024, 9216);

  // Layer 3: in=1024, out=256, K=9216. splitK=16 -> 1024 blocks (kSteps 18).
  kan_prep2<<<dim3(8, 32), 256, 0, stream>>>(coef[3], sb[3], ss[3], Wt, 256, 9216);
  kan_feat<<<4096 * 1024 / 256, 256, 0, stream>>>(actA, F, 10, 9216, 0);
  hipMemsetAsync(d_out, 0, (size_t)out_size * sizeof(float), stream);
  kan_gemm<16><<<dim3(2, 32, 16), 256, 0, stream>>>(F, Wt, out, 256, 9216);
}

// Round 7
// 620.081 us; speedup vs baseline: 1.3303x; 1.1252x over previous
//
#include <hip/hip_runtime.h>
#include <cstdint>
#include <cstddef>

typedef _Float16 f16;
typedef _Float16 f16x4 __attribute__((ext_vector_type(4)));
typedef _Float16 f16x8 __attribute__((ext_vector_type(8)));
typedef float f32x4 __attribute__((ext_vector_type(4)));

// ---------------------------------------------------------------------------
// async global->LDS, 16B per lane. LDS dest is WAVE-UNIFORM base; HW writes
// lane i at base + i*16 (m97/m104 semantics).
// ---------------------------------------------------------------------------
__device__ __forceinline__ void gl2lds16(const void* g, void* l) {
  __builtin_amdgcn_global_load_lds(
      (const __attribute__((address_space(1))) void*)(uintptr_t)g,
      (__attribute__((address_space(3))) void*)(uintptr_t)l,
      16, 0, 0);
}

// ---------------------------------------------------------------------------
// Weight prep via LDS-bounce transpose. Tile 32 o x 32 i per block.
// Wt[o][i*9+0] = sb[i,o]; Wt[o][i*9+1+g] = coef[i,o,g]*ss[i,o].
// ---------------------------------------------------------------------------
__global__ __launch_bounds__(256) void kan_prep2(
    const float* __restrict__ coef, const float* __restrict__ sb,
    const float* __restrict__ ss, f16* __restrict__ Wt,
    int out, int K9)
{
  __shared__ float s_sb[32][32];   // [i][o]
  __shared__ float s_ss[32][32];
  __shared__ f16 s_w[32][288];     // [o][i*9+t]
  const int t  = threadIdx.x;
  const int o0 = blockIdx.x * 32, i0 = blockIdx.y * 32;

  {
    int il = t >> 3, oc = (t & 7) * 4;
    float4 vb = *(const float4*)(sb + (size_t)(i0 + il) * out + o0 + oc);
    float4 vs = *(const float4*)(ss + (size_t)(i0 + il) * out + o0 + oc);
    s_sb[il][oc + 0] = vb.x; s_sb[il][oc + 1] = vb.y;
    s_sb[il][oc + 2] = vb.z; s_sb[il][oc + 3] = vb.w;
    s_ss[il][oc + 0] = vs.x; s_ss[il][oc + 1] = vs.y;
    s_ss[il][oc + 2] = vs.z; s_ss[il][oc + 3] = vs.w;
  }
  __syncthreads();

#pragma unroll
  for (int j = 0; j < 8; ++j) {
    int f  = j * 256 + t;
    int il = f >> 6, c = f & 63;
    int ol = c >> 1, gh = (c & 1) * 4;
    float4 v = *(const float4*)(coef + ((size_t)(i0 + il) * out + (o0 + ol)) * 8 + gh);
    float ssv = s_ss[il][ol];
    f16* dst = &s_w[ol][il * 9 + 1 + gh];
    dst[0] = (f16)(v.x * ssv); dst[1] = (f16)(v.y * ssv);
    dst[2] = (f16)(v.z * ssv); dst[3] = (f16)(v.w * ssv);
  }
#pragma unroll
  for (int j = 0; j < 4; ++j) {
    int e = j * 256 + t; int il = e >> 5, ol = e & 31;
    s_w[ol][il * 9] = (f16)s_sb[il][ol];
  }
  __syncthreads();

  {
    int o = t >> 3, part = t & 7;
    f16* dst = Wt + (size_t)(o0 + o) * K9 + (size_t)i0 * 9 + part * 36;
    const f16* src = &s_w[o][part * 36];
#pragma unroll
    for (int q = 0; q < 9; ++q)
      *(f16x4*)(dst + q * 4) = *(const f16x4*)(src + q * 4);
  }
}

// ---------------------------------------------------------------------------
// Features: per x -> [silu(x), B3_0(x)..B3_7(x)] fp16, row-major F[b][i*9+t].
// Uniform pykan grid hardcoded: t_j = (j-3)*0.4 - 1.
// ---------------------------------------------------------------------------
__global__ __launch_bounds__(256) void kan_feat(
    const float* __restrict__ X, f16* __restrict__ F,
    int shift, int K9, int iBase)
{
  int idx = blockIdx.x * 256 + threadIdx.x;
  int b  = idx >> shift;
  int ii = idx & ((1 << shift) - 1);
  float x = X[idx];

  float sig  = 1.0f / (1.0f + __expf(-x));
  float silu = x * sig;

  float t[12];
#pragma unroll
  for (int j = 0; j < 12; ++j) t[j] = (float)(j - 3) * 0.4f - 1.0f;
  float b0[11];
#pragma unroll
  for (int j = 0; j < 11; ++j)
    b0[j] = (x >= t[j] && x < t[j + 1]) ? 1.0f : 0.0f;
  float b1[10];
#pragma unroll
  for (int j = 0; j < 10; ++j)
    b1[j] = (x - t[j]) * 2.5f * b0[j] + (t[j + 2] - x) * 2.5f * b0[j + 1];
  float b2[9];
#pragma unroll
  for (int j = 0; j < 9; ++j)
    b2[j] = (x - t[j]) * 1.25f * b1[j] + (t[j + 3] - x) * 1.25f * b1[j + 1];
  float b3[8];
#pragma unroll
  for (int j = 0; j < 8; ++j)
    b3[j] = (x - t[j]) * (1.0f / 1.2f) * b2[j] +
            (t[j + 4] - x) * (1.0f / 1.2f) * b2[j + 1];

  f16* o = F + (size_t)b * K9 + (size_t)(iBase + ii) * 9;
  o[0] = (f16)silu;
#pragma unroll
  for (int g = 0; g < 8; ++g) o[1 + g] = (f16)b3[g];
}

// ---------------------------------------------------------------------------
// GEMM: C[M,N] += A[M,K] * Bt[N,K]^T, fp16 in / fp32 out.
// Block 128x128, BK=32, 4 waves (2x2), wave tile 64x64, acc[4][4].
// RING-4 PIPELINE, issue-ahead 3 (R6 post-mortem: one-barrier dbuf pays full
// ~900cy HBM latency per step because loads are issued only ~310cy before the
// compiler's vmcnt(0) barrier drain; R5's depth-2 was 620cy — still short).
// Steady state per step: s_waitcnt vmcnt(8)  [step-s's 4 loads done; s+1,s+2
// in flight]; s_barrier; issue step-s+3 into buf freed by this barrier;
// ds_read frags; 16 MFMA. Loads fly 3*310 ~= 930cy before their wait.
// Safety: frags are in regs (compiler lgkm-before-MFMA) before a wave reaches
// the next barrier, so buf[(s+3)%4]=buf[(s-1)%4] is free when reused; vmcnt
// is per-wave but all waves issue symmetrically; barrier orders reuse.
// XOR swizzle chunk^=((row>>1)&3) at source: R4-R6 verified 0 conflicts.
// LDS 64KB -> exactly 2 blocks/CU; grids sized 512 so all blocks co-resident.
// ---------------------------------------------------------------------------
template <int SPLITK>
__global__ __launch_bounds__(256, 2) void kan_gemm(
    const f16* __restrict__ A, const f16* __restrict__ Bt,
    float* __restrict__ C, int N, int K)
{
  __shared__ __align__(16) f16 lds[4][8192];  // ring: [buf][ A:128x32 | B:128x32 ]
  const int tid   = threadIdx.x;
  const int lane  = tid & 63;
  const int w     = tid >> 6;
  const int waveM = w >> 1, waveN = w & 1;
  const int l16   = lane & 15, quad = lane >> 4;
  const size_t mBase = (size_t)blockIdx.y * 128;
  const size_t nBase = (size_t)blockIdx.x * 128;
  const int kChunk = K / SPLITK;
  const int k0     = blockIdx.z * kChunk;
  const int kSteps = kChunk >> 5;

  // staging: A = 512 chunks of 16B (2/thread), B same. Swizzled at source.
  const f16* gA[2]; int lA[2];
  const f16* gB[2]; int lB[2];
#pragma unroll
  for (int r = 0; r < 2; ++r) {
    int g = r * 256 + tid, row = g >> 2;
    int cs = (g & 3) ^ ((row >> 1) & 3);
    gA[r] = A + (mBase + row) * (size_t)K + k0 + cs * 8;
    gB[r] = Bt + (nBase + row) * (size_t)K + k0 + cs * 8;
    lA[r] = (r * 256 + (tid & ~63)) * 8;
    lB[r] = 4096 + lA[r];
  }

  f32x4 acc[4][4] = {};

  // preload steps 0..2 into bufs 0..2 (kSteps >= 18 in all our shapes)
#pragma unroll
  for (int p = 0; p < 3; ++p) {
    f16* b = lds[p];
    int kk = p * 32;
#pragma unroll
    for (int r = 0; r < 2; ++r) {
      gl2lds16(gA[r] + kk, b + lA[r]);
      gl2lds16(gB[r] + kk, b + lB[r]);
    }
  }

  for (int s = 0; s < kSteps; ++s) {
    // drain step-s's 4 loads only; keep later steps in flight (tail: fewer)
    if (s < kSteps - 2)       asm volatile("s_waitcnt vmcnt(8)" ::: "memory");
    else if (s == kSteps - 2) asm volatile("s_waitcnt vmcnt(4)" ::: "memory");
    else                      asm volatile("s_waitcnt vmcnt(0)" ::: "memory");
    __builtin_amdgcn_s_barrier();

    if (s + 3 < kSteps) {  // refill the buffer freed by the barrier above
      int kk = (s + 3) * 32;
      f16* b = lds[(s + 3) & 3];
#pragma unroll
      for (int r = 0; r < 2; ++r) {
        gl2lds16(gA[r] + kk, b + lA[r]);
        gl2lds16(gB[r] + kk, b + lB[r]);
      }
    }

    const f16* buf = lds[s & 3];
    f16x8 af[4], bf[4];
#pragma unroll
    for (int mi = 0; mi < 4; ++mi) {
      int row = waveM * 64 + mi * 16 + l16;
      af[mi] = *(const f16x8*)(buf + row * 32 + (quad ^ ((row >> 1) & 3)) * 8);
    }
#pragma unroll
    for (int ni = 0; ni < 4; ++ni) {
      int col = waveN * 64 + ni * 16 + l16;
      bf[ni] = *(const f16x8*)(buf + 4096 + col * 32 + (quad ^ ((col >> 1) & 3)) * 8);
    }
#pragma unroll
    for (int mi = 0; mi < 4; ++mi)
#pragma unroll
      for (int ni = 0; ni < 4; ++ni)
        acc[mi][ni] = __builtin_amdgcn_mfma_f32_16x16x32_f16(
            af[mi], bf[ni], acc[mi][ni], 0, 0, 0);
  }

#pragma unroll
  for (int mi = 0; mi < 4; ++mi) {
    size_t row = mBase + waveM * 64 + mi * 16 + quad * 4;
#pragma unroll
    for (int ni = 0; ni < 4; ++ni) {
      size_t col = nBase + waveN * 64 + ni * 16 + l16;
#pragma unroll
      for (int r = 0; r < 4; ++r)
        unsafeAtomicAdd(C + (row + r) * N + col, acc[mi][ni][r]);
    }
  }
}

// ---------------------------------------------------------------------------
// Orchestration. WS: Wt (18.9MB) | F (75.5MB) | actA | actB (16.8MB each).
// All GEMM grids = 512 blocks -> exactly 2 resident/CU (LDS 64KB cap 2),
// every block co-resident, no dispatch tail.
// ---------------------------------------------------------------------------
extern "C" void kernel_launch(void* const* d_in, const int* in_sizes, int n_in,
                              void* d_out, int out_size, void* d_ws, size_t ws_size,
                              hipStream_t stream)
{
  const float* y = (const float*)d_in[0];
  const float* u = (const float*)d_in[1];
  const float* coef[4]; const float* sb[4]; const float* ss[4];
  for (int l = 0; l < 4; ++l) {
    coef[l] = (const float*)d_in[2 + 4 * l];
    sb[l]   = (const float*)d_in[3 + 4 * l];
    ss[l]   = (const float*)d_in[4 + 4 * l];
  }
  char* ws = (char*)d_ws;
  f16*   Wt   = (f16*)(ws);
  f16*   F    = (f16*)(ws + 18874368);                        // 9216*1024*2
  float* actA = (float*)(ws + 18874368 + 75497472);           // + 4096*9216*2
  float* actB = (float*)(ws + 18874368 + 75497472 + 16777216);
  float* out  = (float*)d_out;
  const size_t actBytes = (size_t)4096 * 1024 * 4;

  // Layer 0: in=512 (concat y|u), out=1024, K=4608. splitK=2 (kSteps 72).
  kan_prep2<<<dim3(32, 16), 256, 0, stream>>>(coef[0], sb[0], ss[0], Wt, 1024, 4608);
  kan_feat<<<4096 * 256 / 256, 256, 0, stream>>>(y, F, 8, 4608, 0);
  kan_feat<<<4096 * 256 / 256, 256, 0, stream>>>(u, F, 8, 4608, 256);
  hipMemsetAsync(actA, 0, actBytes, stream);
  kan_gemm<2><<<dim3(8, 32, 2), 256, 0, stream>>>(F, Wt, actA, 1024, 4608);

  // Layer 1: in=1024, out=1024, K=9216. splitK=2 (kSteps 144).
  kan_prep2<<<dim3(32, 32), 256, 0, stream>>>(coef[1], sb[1], ss[1], Wt, 1024, 9216);
  kan_feat<<<4096 * 1024 / 256, 256, 0, stream>>>(actA, F, 10, 9216, 0);
  hipMemsetAsync(actB, 0, actBytes, stream);
  kan_gemm<2><<<dim3(8, 32, 2), 256, 0, stream>>>(F, Wt, actB, 1024, 9216);

  // Layer 2: in=1024, out=1024, K=9216. splitK=2.
  kan_prep2<<<dim3(32, 32), 256, 0, stream>>>(coef[2], sb[2], ss[2], Wt, 1024, 9216);
  kan_feat<<<4096 * 1024 / 256, 256, 0, stream>>>(actB, F, 10, 9216, 0);
  hipMemsetAsync(actA, 0, actBytes, stream);
  kan_gemm<2><<<dim3(8, 32, 2), 256, 0, stream>>>(F, Wt, actA, 1024, 9216);

  // Layer 3: in=1024, out=256, K=9216. splitK=8 -> 512 blocks (kSteps 36).
  kan_prep2<<<dim3(8, 32), 256, 0, stream>>>(coef[3], sb[3], ss[3], Wt, 256, 9216);
  kan_feat<<<4096 * 1024 / 256, 256, 0, stream>>>(actA, F, 10, 9216, 0);
  hipMemsetAsync(d_out, 0, (size_t)out_size * sizeof(float), stream);
  kan_gemm<8><<<dim3(2, 32, 8), 256, 0, stream>>>(F, Wt, out, 256, 9216);
}